// Round 10
// baseline (27.570 us; speedup 1.0000x reference)
//
#include <hip/hip_runtime.h>
#include <math.h>

// Voxelized chamfer via bf16 MFMA with algebra folded into unused K-slots.
// SINGLE dispatch: R8's proven MFMA kernel + in-kernel last-block reduction.
//
//   vox coords are integer-valued fp32, |v| <= ~160 -> EXACT in bf16.
//   A row i : {-2qx, -2qy, -2qz, 1, 1, 0...}   (-2q = exponent shift, exact)
//   B col j : { cx,   cy,   cz, yh, yl, 0...}  (yy = yh+yl exact bf16 split)
//   MFMA   -> yy_j - 2 q_i.c_j  directly (all |vals| < 2^24: fp32-exact).
//   row-min_j (that) + xx_i = chamfer row-min. Epilogue = 1 min3 / 2 evals.
//   loss = mean(row-mins, pred->gt) + mean(row-mins, gt->pred).
//
// 512 blocks = (dir, batch, 64-query tile). Stage all 4096 candidates as
// pre-packed 16B B-frags in LDS (ALL IEEE divides here, bit-identical to the
// reference). Each of 4 waves scans 64 col-tiles in pairs: 2 ds_read_b128 +
// 8 MFMA + 16 min3. Row-min wrap-up: 4-level shfl min, +xx, cross-wave LDS
// min, exact int sum -> partials[bid] (1 float per block).
// Finish (fused): partials write -> __threadfence (release: L2 writeback) ->
// ticket atomicAdd. The 512th ticket's block acquire-fences and volatile-
// reads all 512 partials (its XCD's L2 never cached them -> no stale lines),
// fixed-order tree sum, out[0] = sum * 2^-14. Deterministic output: the sum
// order is fixed regardless of WHICH block reduces; every partial is an
// exact integer, scale 2^-14 exact. Ticket trick is base-independent: each
// call adds exactly 512 tickets -> exactly one block sees residue 511, so
// the persistent counter (poisoned or not) never needs resetting.
//
// Exactness: yy <= ~3*160^2 < 2^17; yh = 256*floor(yy/256) (multiplier has
// <=9 sig bits -> bf16-exact), yl in [0,256) integer -> bf16-exact; -2q even
// |.| <= 512 -> bf16-exact. MFMA products <= ~2^17, 5-term fp32 accum exact.

typedef float  f32x4  __attribute__((ext_vector_type(4)));
typedef short  bf16x8 __attribute__((ext_vector_type(8)));

constexpr int NPTS  = 4096;
constexpr int BLK   = 256;
constexpr int QPB   = 64;             // query rows per block
constexpr int NTB   = NPTS / QPB;     // 64 row tiles per (dir, batch)
constexpr int BATCH = 4;
constexpr int NBLOCKS = 2 * BATCH * NTB;   // 512
constexpr float FINF  = 3.402823466e38f;
constexpr float SCALE = 1.0f / 16384.0f;   // 1/(B*N) = 2^-14, exact

__device__ __forceinline__ float vox(float c, float off) {
    return truncf((c + off) / 0.05f);  // IEEE div: bit-matches reference
}
__device__ __forceinline__ unsigned bfbits(float v) {
    return __float_as_uint(v) >> 16;   // exact for the value classes above
}
__device__ __forceinline__ float min3(float a, float b, float c) {
    return fminf(fminf(a, b), c);      // clang fuses to v_min3_f32
}

__global__ __launch_bounds__(BLK) void chamfer_fused_kernel(
    const float* __restrict__ preds,
    const float* __restrict__ gts,
    float* __restrict__ partials,      // [512]
    unsigned* __restrict__ ticket,     // persistent ticket counter
    float* __restrict__ out)
{
    __shared__ int4  cfrag[NPTS];      // candidate B-frags (64 KB)
    __shared__ int4  qfrag[QPB];       // query A-frags (prescaled -2, ones)
    __shared__ float qxx[QPB];         // query squared norms (exact ints)
    __shared__ float waveRow[4][QPB];
    __shared__ int   lastFlag;
    __shared__ float s1[BLK];

    const int t    = threadIdx.x;
    const int bid  = blockIdx.x;        // dir*256 + b*64 + tile
    const int dir  = bid >> 8;
    const int rem  = bid & 255;
    const int b    = rem >> 6;
    const int tile = rem & 63;
    const int w    = t >> 6;
    const int lane = t & 63;

    const float* __restrict__ xb = (dir ? gts : preds) + (size_t)b * NPTS * 3;
    const float* __restrict__ yb = (dir ? preds : gts) + (size_t)b * NPTS * 3;

    constexpr unsigned ONE = 0x3F80u;   // bf16 1.0

    // ---- stage candidates: voxelize, norms, split, pack B-frags ----
    for (int j = t; j < NPTS; j += BLK) {
        const float x = vox(yb[j*3+0], 3.0f);
        const float y = vox(yb[j*3+1], 3.0f);
        const float z = vox(yb[j*3+2], 1.0f);
        const float yy = fmaf(z, z, fmaf(y, y, x * x));      // exact int
        const float hi = floorf(yy * 0.00390625f) * 256.0f;  // exact
        const float lo = yy - hi;                            // in [0,256)
        cfrag[j] = make_int4(
            (int)((bfbits(y) << 16) | bfbits(x)),            // k0:cx k1:cy
            (int)((bfbits(hi) << 16) | bfbits(z)),           // k2:cz k3:yh
            (int)(bfbits(lo)),                               // k4:yl k5:0
            0);
    }
    // ---- stage this block's 64 query rows as A-frags ----
    if (t < QPB) {
        const int qi = tile * QPB + t;
        const float x = vox(xb[qi*3+0], 3.0f);
        const float y = vox(xb[qi*3+1], 3.0f);
        const float z = vox(xb[qi*3+2], 1.0f);
        qxx[t] = fmaf(z, z, fmaf(y, y, x * x));
        const float mx = -2.0f * x, my = -2.0f * y, mz = -2.0f * z; // exact
        qfrag[t] = make_int4(
            (int)((bfbits(my) << 16) | bfbits(mx)),          // k0 k1
            (int)((ONE << 16) | bfbits(mz)),                 // k2 k3:1
            (int)(ONE),                                      // k4:1 k5:0
            0);
    }
    __syncthreads();

    const int lq  = lane & 15;          // row (A) / col (B) within 16-tile
    const int grp = lane >> 4;          // lane group 0..3
    const bool lo_g = (grp == 0);       // k=0..7 carrier group

    // A fragments for the four 16-row query tiles (k-slots 8..31 = +0.0).
    bf16x8 afrag[4];
    #pragma unroll
    for (int rt = 0; rt < 4; ++rt) {
        const int4 qv = qfrag[rt * 16 + lq];
        int4 ai = { lo_g ? qv.x : 0, lo_g ? qv.y : 0, lo_g ? qv.z : 0, 0 };
        afrag[rt] = __builtin_bit_cast(bf16x8, ai);
    }

    f32x4 rm[4];
    #pragma unroll
    for (int rt = 0; rt < 4; ++rt) rm[rt] = (f32x4){FINF, FINF, FINF, FINF};
    const f32x4 zero = (f32x4){0.f, 0.f, 0.f, 0.f};

    // ---- main loop: 64 col-tiles per wave, processed in pairs ----
    #pragma unroll 2
    for (int jp = w * 32; jp < w * 32 + 32; ++jp) {
        const int jA = jp * 2, jB = jA + 1;
        const int4 bva = cfrag[jA * 16 + lq];   // b128, 4-way broadcast
        const int4 bvb = cfrag[jB * 16 + lq];
        const bf16x8 bfa = __builtin_bit_cast(bf16x8, bva);
        const bf16x8 bfb = __builtin_bit_cast(bf16x8, bvb);

        f32x4 dA[4], dB[4];
        #pragma unroll
        for (int rt = 0; rt < 4; ++rt)
            dA[rt] = __builtin_amdgcn_mfma_f32_16x16x32_bf16(
                afrag[rt], bfa, zero, 0, 0, 0);
        #pragma unroll
        for (int rt = 0; rt < 4; ++rt)
            dB[rt] = __builtin_amdgcn_mfma_f32_16x16x32_bf16(
                afrag[rt], bfb, zero, 0, 0, 0);

        #pragma unroll
        for (int rt = 0; rt < 4; ++rt) {
            #pragma unroll
            for (int i = 0; i < 4; ++i)
                rm[rt][i] = min3(rm[rt][i], dA[rt][i], dB[rt][i]);
        }
    }

    // ---- row-min wrap-up: min over the 16 cols held across lq lanes ----
    #pragma unroll
    for (int rt = 0; rt < 4; ++rt) {
        #pragma unroll
        for (int i = 0; i < 4; ++i) {
            float v = rm[rt][i];
            v = fminf(v, __shfl_xor(v, 1, 64));
            v = fminf(v, __shfl_xor(v, 2, 64));
            v = fminf(v, __shfl_xor(v, 4, 64));
            v = fminf(v, __shfl_xor(v, 8, 64));
            const int r = rt * 16 + grp * 4 + i;   // C/D row map (m89/m91)
            if (lq == 0) waveRow[w][r] = v + qxx[r];
        }
    }
    __syncthreads();

    if (w == 0) {                       // lane r owns query row r
        float v = fminf(fminf(waveRow[0][lane], waveRow[1][lane]),
                        fminf(waveRow[2][lane], waveRow[3][lane]));
        #pragma unroll
        for (int o = 32; o >= 1; o >>= 1) v += __shfl_xor(v, o, 64);
        if (lane == 0) {
            partials[bid] = v;          // exact int sum of 64 row-mins
            __threadfence();            // release: partial visible device-wide
            const unsigned old = atomicAdd(ticket, 1u);
            lastFlag = ((old & (NBLOCKS - 1)) == (NBLOCKS - 1)) ? 1 : 0;
        }
    }
    __syncthreads();

    // ---- fused finish: the last-ticketed block does the final reduce ----
    if (lastFlag) {
        __threadfence();                               // acquire
        volatile const float* vp = partials;
        s1[t] = vp[t] + vp[t + 256];                   // fixed-order pairs
        __syncthreads();
        for (int k = 128; k > 0; k >>= 1) {
            if (t < k) s1[t] += s1[t + k];
            __syncthreads();
        }
        if (t == 0) out[0] = s1[0] * SCALE;            // overwrite, exact
    }
}

extern "C" void kernel_launch(void* const* d_in, const int* in_sizes, int n_in,
                              void* d_out, int out_size, void* d_ws, size_t ws_size,
                              hipStream_t stream)
{
    const float* preds = (const float*)d_in[0];
    const float* gts   = (const float*)d_in[1];
    float* out = (float*)d_out;

    float*    partials = (float*)d_ws;                    // 512 floats
    unsigned* ticket   = (unsigned*)(partials + NBLOCKS); // 1 uint, persistent

    chamfer_fused_kernel<<<NBLOCKS, BLK, 0, stream>>>(
        preds, gts, partials, ticket, out);
}